// Round 12
// baseline (137.265 us; speedup 1.0000x reference)
//
#include <hip/hip_runtime.h>
#include <hip/hip_bf16.h>
#include <math.h>

// Problem constants (from reference setup)
#define DHID 320     // hidden dim D
#define KNN  30      // neighbors per node

typedef float f4    __attribute__((ext_vector_type(4)));
typedef float f32x4 __attribute__((ext_vector_type(4)));
typedef short bf16x8 __attribute__((ext_vector_type(8)));
typedef short bf16x4 __attribute__((ext_vector_type(4)));

// fp32 -> bf16 bits, round-to-nearest-even
static __device__ __forceinline__ short f2bf(float x) {
    union { float f; unsigned u; } v; v.f = x;
    unsigned r = v.u + 0x7FFFu + ((v.u >> 16) & 1u);
    return (short)(r >> 16);
}
// bf16 bits -> fp32
static __device__ __forceinline__ float bf2f(short s) {
    union { float f; unsigned u; } v;
    v.u = ((unsigned)(unsigned short)s) << 16;
    return v.f;
}

// ---------------------------------------------------------------------------
// Kernel 0: one-pass convert: W1,W2 -> fragment-blocked bf16; h -> bf16 hb.
// Blocked layout: dst[tile*NT*512 + t*512 + kg*128 + lrow*8 + j] -> one wave
// B-load = contiguous 1 KiB.
// ---------------------------------------------------------------------------
__global__ __launch_bounds__(256)
void conv_kernel(const float* __restrict__ W1, const float* __restrict__ W2,
                 const float* __restrict__ h,
                 short* __restrict__ Wt1, short* __restrict__ Wt2,
                 short* __restrict__ hb, int N)
{
    int i = blockIdx.x * 256 + threadIdx.x;
    if (i < 640 * 320) {
        int k = i / 320, c = i - k * 320;               // W1[k][c]
        int tile = c >> 4, lr = c & 15;
        int t = k >> 5, kg = (k >> 3) & 3, j = k & 7;
        Wt1[(size_t)tile * (20 * 512) + t * 512 + kg * 128 + lr * 8 + j] = f2bf(W1[i]);
    } else if (i < 640 * 320 + 320 * 320) {
        int q = i - 640 * 320;
        int k = q / 320, c = q - k * 320;               // W2[k][c]
        int tile = c >> 4, lr = c & 15;
        int t = k >> 5, kg = (k >> 3) & 3, j = k & 7;
        Wt2[(size_t)tile * (10 * 512) + t * 512 + kg * 128 + lr * 8 + j] = f2bf(W2[q]);
    } else {
        int q = i - (640 * 320 + 320 * 320);
        if (q < N * DHID) hb[q] = f2bf(h[q]);
    }
}

// ---------------------------------------------------------------------------
// Kernel A: per-node attention + aggregation + coord update (one wave/node).
// Online softmax over K=30 edges. Gather reads the bf16 copy hb (10 B/lane
// per row instead of 20 B — halves the L2-fill stream; 5.25 MB working set).
// Self-row and coords stay fp32; dot/softmax accumulate in fp32.
// ---------------------------------------------------------------------------
__global__ __launch_bounds__(256)
void edge_kernel(const float* __restrict__ h,
                 const short* __restrict__ hb,
                 const float* __restrict__ coord,
                 const int*   __restrict__ col,       // edge_index row 1
                 short*       __restrict__ aggb,      // [N, D] bf16 out
                 float*       __restrict__ coord_out, // [N, 3] out
                 int N)
{
    int wid  = (int)((blockIdx.x * 256u + threadIdx.x) >> 6);
    int lane = threadIdx.x & 63;
    if (wid >= N) return;

    const float* hi = h + (size_t)wid * DHID;
    f4    hv = *(const f4*)(hi + 4 * lane);
    float ht = hi[256 + lane];

    float cx = coord[3 * wid + 0];
    float cy = coord[3 * wid + 1];
    float cz = coord[3 * wid + 2];

    // load the 30 neighbor indices + their coords once (lanes 0..29)
    const int* cp = col + (size_t)wid * KNN;
    int jv = (lane < KNN) ? cp[lane] : 0;
    float pjx = 0.f, pjy = 0.f, pjz = 0.f;
    if (lane < KNN) {
        pjx = coord[3 * jv + 0];
        pjy = coord[3 * jv + 1];
        pjz = coord[3 * jv + 2];
    }

    float run_m = -INFINITY, run_l = 0.f;
    f4    accv = {0.f, 0.f, 0.f, 0.f};
    float acct = 0.f;
    float ax = 0.f, ay = 0.f, az = 0.f;

#pragma unroll 2
    for (int k = 0; k < KNN; ++k) {
        int j = __shfl(jv, k);
        const short* hj = hb + (size_t)j * DHID;
        bf16x4 gb = *(const bf16x4*)(hj + 4 * lane);   // 8 B
        float  gt = bf2f(hj[256 + lane]);              // 2 B
        f4 gv = { bf2f(gb[0]), bf2f(gb[1]), bf2f(gb[2]), bf2f(gb[3]) };

        float dot = hv[0] * gv[0];
        dot = fmaf(hv[1], gv[1], dot);
        dot = fmaf(hv[2], gv[2], dot);
        dot = fmaf(hv[3], gv[3], dot);
        dot = fmaf(ht, gt, dot);
        // butterfly: all 64 lanes end with the full 320-dot
#pragma unroll
        for (int off = 32; off; off >>= 1) dot += __shfl_xor(dot, off);

        float dx = cx - __shfl(pjx, k);
        float dy = cy - __shfl(pjy, k);
        float dz = cz - __shfl(pjz, k);
        float radial = dx * dx + dy * dy + dz * dz;
        float s = dot + 1.0f / (radial + 1e-8f);   // DIST_W = 1.0, EPS = 1e-8

        float nm = fmaxf(run_m, s);
        float sc = __expf(run_m - nm);             // first iter: exp(-inf)=0
        float w  = __expf(s - nm);
        run_l = run_l * sc + w;
        accv  = accv * sc + w * gv;
        acct  = acct * sc + w * gt;
        ax = ax * sc + w * dx;
        ay = ay * sc + w * dy;
        az = az * sc + w * dz;
        run_m = nm;
    }

    float inv = 1.0f / run_l;
    short* ao = aggb + (size_t)wid * DHID;
    bf16x4 o;
#pragma unroll
    for (int i = 0; i < 4; ++i) o[i] = f2bf(accv[i] * inv);
    *(bf16x4*)(ao + 4 * lane) = o;                // 8B store
    ao[256 + lane] = f2bf(acct * inv);

    if (lane == 0) {
        float s = inv / (float)KNN;   // mean over K of softmax-weighted diffs
        coord_out[3 * wid + 0] = cx + ax * s;
        coord_out[3 * wid + 1] = cy + ay * s;
        coord_out[3 * wid + 2] = cz + az * s;
    }
}

// ---------------------------------------------------------------------------
// Fused MLP: hout = silu([h|agg]@W1+b1)@W2 + b2 + h
// 512 threads = 8 waves, 32 rows/block, grid N/32 = 256.
// Wave w: row-tile rt = w&1 (16 rows), col-set cs = w>>1 -> col-tiles
// {5cs..5cs+4} in BOTH GEMMs. 5 independent MFMA chains/wave (ILP);
// waves with equal cs share B-fragments (L1 hits); per-block B-traffic
// (600 KiB) now amortized over 32 rows -> total B stream halved vs 16-row.
// z/h1 staged in XOR-swizzled LDS (validated addressing, 60 KiB total).
// ---------------------------------------------------------------------------
__global__ __launch_bounds__(512)
void mlp_fused_kernel(const float* __restrict__ h,
                      const short* __restrict__ hb,
                      const short* __restrict__ aggb,
                      const short* __restrict__ Wt1,
                      const short* __restrict__ Wt2,
                      const float* __restrict__ b1,
                      const float* __restrict__ b2,
                      float*       __restrict__ hout)
{
    __shared__ short zs[32 * 640];      // [32][640] bf16, swizzled, 40 KiB
    __shared__ short h1s[32 * 320];     // [32][320] bf16, swizzled, 20 KiB

    const int tid  = threadIdx.x;
    const int lane = tid & 63;
    const int wv   = tid >> 6;          // 0..7
    const int rt   = wv & 1;            // row-tile 0/1
    const int cs   = wv >> 1;           // col-set 0..3
    const int lrow = lane & 15;
    const int kg   = lane >> 4;
    const int r0   = blockIdx.x * 32;

    // stage z = [hb | aggb]: 32 rows x 80 chunks of 8 shorts = 2560 chunks
    for (int c = tid; c < 2560; c += 512) {
        int row = c / 80;
        int zc  = (c - row * 80) * 8;   // 0..632
        int sw  = (row & 7) << 4;
        bf16x8 v;
        if (zc < DHID) {
            v = *(const bf16x8*)(hb + (size_t)(r0 + row) * DHID + zc);
        } else {
            v = *(const bf16x8*)(aggb + (size_t)(r0 + row) * DHID + (zc - DHID));
        }
        *(bf16x8*)((char*)zs + ((row * 1280 + zc * 2) ^ sw)) = v;
    }
    __syncthreads();

    const int   sw    = (lrow & 7) << 4;
    const char* abase = (const char*)zs + (rt * 16 + lrow) * 1280;

    // ---- GEMM1: [32 x 640] @ W1, 5 col-tiles/wave, 20 K-steps ----
    f32x4 acc[5] = {};
    {
        const short* B = Wt1 + (size_t)(cs * 5) * (20 * 512) + kg * 128 + lrow * 8;
        for (int t = 0; t < 20; ++t) {
            bf16x8 a = *(const bf16x8*)(abase + ((t * 64 + kg * 16) ^ sw));
#pragma unroll
            for (int i = 0; i < 5; ++i) {
                bf16x8 b = *(const bf16x8*)(B + (size_t)i * (20 * 512) + t * 512);
                acc[i] = __builtin_amdgcn_mfma_f32_16x16x32_bf16(a, b, acc[i], 0, 0, 0);
            }
        }
    }

    // epilogue 1: bias + SiLU -> swizzled h1s (rows rt*16 + kg*4 + r)
#pragma unroll
    for (int i = 0; i < 5; ++i) {
        int colc = (cs * 5 + i) * 16 + lrow;
        float bb = b1[colc];
#pragma unroll
        for (int r = 0; r < 4; ++r) {
            int row = rt * 16 + kg * 4 + r;
            float x = acc[i][r] + bb;
            x = x / (1.f + __expf(-x));
            *(short*)((char*)h1s + ((row * 640 + colc * 2) ^ ((row & 7) << 4))) = f2bf(x);
        }
    }
    __syncthreads();

    // ---- GEMM2: [32 x 320] @ W2, 5 col-tiles/wave, 10 K-steps ----
    f32x4 acc2[5] = {};
    {
        const short* B = Wt2 + (size_t)(cs * 5) * (10 * 512) + kg * 128 + lrow * 8;
        const char* a2base = (const char*)h1s + (rt * 16 + lrow) * 640;
        for (int t = 0; t < 10; ++t) {
            bf16x8 a = *(const bf16x8*)(a2base + ((t * 64 + kg * 16) ^ sw));
#pragma unroll
            for (int i = 0; i < 5; ++i) {
                bf16x8 b = *(const bf16x8*)(B + (size_t)i * (10 * 512) + t * 512);
                acc2[i] = __builtin_amdgcn_mfma_f32_16x16x32_bf16(a, b, acc2[i], 0, 0, 0);
            }
        }
    }

    // epilogue 2: bias + residual (fp32 h re-read) -> hout
#pragma unroll
    for (int i = 0; i < 5; ++i) {
        int colc = (cs * 5 + i) * 16 + lrow;
        float bb = b2[colc];
#pragma unroll
        for (int r = 0; r < 4; ++r) {
            int grow = r0 + rt * 16 + kg * 4 + r;
            hout[(size_t)grow * DHID + colc] =
                acc2[i][r] + bb + h[(size_t)grow * DHID + colc];
        }
    }
}

// ---------------------------------------------------------------------------
extern "C" void kernel_launch(void* const* d_in, const int* in_sizes, int n_in,
                              void* d_out, int out_size, void* d_ws, size_t ws_size,
                              hipStream_t stream)
{
    const float* h     = (const float*)d_in[0];
    const float* coord = (const float*)d_in[1];
    const float* W1    = (const float*)d_in[2];
    const float* b1    = (const float*)d_in[3];
    const float* W2    = (const float*)d_in[4];
    const float* b2    = (const float*)d_in[5];
    const int*   ei    = (const int*)d_in[6];   // [2, N*K] int32

    const int N  = in_sizes[0] / DHID;          // 8192
    const int NK = N * KNN;

    float* out       = (float*)d_out;
    float* hout      = out;                     // [N, 320]
    float* coord_out = out + (size_t)N * DHID;  // [N, 3]

    // ws layout (shorts): aggb[N*320] | Wt1[204800] | Wt2[102400] | hb[N*320]
    // = 11.1 MB total (d_ws observed ~268 MB via harness poison fills).
    short* aggb = (short*)d_ws;
    short* Wt1  = aggb + (size_t)N * DHID;
    short* Wt2  = Wt1 + 20 * 20 * 512;
    short* hb   = Wt2 + 20 * 10 * 512;

    const int* col = ei + NK;                   // second row of edge_index

    const int conv_elems = 640 * 320 + 320 * 320 + N * DHID;
    conv_kernel<<<(conv_elems + 255) / 256, 256, 0, stream>>>(W1, W2, h, Wt1, Wt2, hb, N);
    edge_kernel<<<N / 4, 256, 0, stream>>>(h, hb, coord, col, aggb, coord_out, N);
    mlp_fused_kernel<<<N / 32, 512, 0, stream>>>(h, hb, aggb, Wt1, Wt2, b1, b2, hout);
}

// Round 16
// 137.045 us; speedup vs baseline: 1.0016x; 1.0016x over previous
//
#include <hip/hip_runtime.h>
#include <hip/hip_bf16.h>
#include <math.h>

// Problem constants (from reference setup)
#define DHID 320     // hidden dim D
#define KNN  30      // neighbors per node

typedef float f4    __attribute__((ext_vector_type(4)));
typedef float f32x4 __attribute__((ext_vector_type(4)));
typedef short bf16x8 __attribute__((ext_vector_type(8)));
typedef short bf16x4 __attribute__((ext_vector_type(4)));

// fp32 -> bf16 bits, round-to-nearest-even
static __device__ __forceinline__ short f2bf(float x) {
    union { float f; unsigned u; } v; v.f = x;
    unsigned r = v.u + 0x7FFFu + ((v.u >> 16) & 1u);
    return (short)(r >> 16);
}
// bf16 bits -> fp32
static __device__ __forceinline__ float bf2f(short s) {
    union { float f; unsigned u; } v;
    v.u = ((unsigned)(unsigned short)s) << 16;
    return v.f;
}

// ---------------------------------------------------------------------------
// Kernel 0: one-pass convert: W1,W2 -> fragment-blocked bf16; h -> bf16 hb.
// Blocked layout: dst[tile*NT*512 + t*512 + kg*128 + lrow*8 + j] -> one wave
// B-load = contiguous 1 KiB.
// ---------------------------------------------------------------------------
__global__ __launch_bounds__(256)
void conv_kernel(const float* __restrict__ W1, const float* __restrict__ W2,
                 const float* __restrict__ h,
                 short* __restrict__ Wt1, short* __restrict__ Wt2,
                 short* __restrict__ hb, int N)
{
    int i = blockIdx.x * 256 + threadIdx.x;
    if (i < 640 * 320) {
        int k = i / 320, c = i - k * 320;               // W1[k][c]
        int tile = c >> 4, lr = c & 15;
        int t = k >> 5, kg = (k >> 3) & 3, j = k & 7;
        Wt1[(size_t)tile * (20 * 512) + t * 512 + kg * 128 + lr * 8 + j] = f2bf(W1[i]);
    } else if (i < 640 * 320 + 320 * 320) {
        int q = i - 640 * 320;
        int k = q / 320, c = q - k * 320;               // W2[k][c]
        int tile = c >> 4, lr = c & 15;
        int t = k >> 5, kg = (k >> 3) & 3, j = k & 7;
        Wt2[(size_t)tile * (10 * 512) + t * 512 + kg * 128 + lr * 8 + j] = f2bf(W2[q]);
    } else {
        int q = i - (640 * 320 + 320 * 320);
        if (q < N * DHID) hb[q] = f2bf(h[q]);
    }
}

// ---------------------------------------------------------------------------
// Kernel A: per-node attention + aggregation + coord update (one wave/node).
// Online softmax over K=30 edges; gather reads bf16 hb (halved L2/HBM
// stream vs fp32).
// ---------------------------------------------------------------------------
__global__ __launch_bounds__(256)
void edge_kernel(const float* __restrict__ h,
                 const short* __restrict__ hb,
                 const float* __restrict__ coord,
                 const int*   __restrict__ col,       // edge_index row 1
                 short*       __restrict__ aggb,      // [N, D] bf16 out
                 float*       __restrict__ coord_out, // [N, 3] out
                 int N)
{
    int wid  = (int)((blockIdx.x * 256u + threadIdx.x) >> 6);
    int lane = threadIdx.x & 63;
    if (wid >= N) return;

    const float* hi = h + (size_t)wid * DHID;
    f4    hv = *(const f4*)(hi + 4 * lane);
    float ht = hi[256 + lane];

    float cx = coord[3 * wid + 0];
    float cy = coord[3 * wid + 1];
    float cz = coord[3 * wid + 2];

    // load the 30 neighbor indices + their coords once (lanes 0..29)
    const int* cp = col + (size_t)wid * KNN;
    int jv = (lane < KNN) ? cp[lane] : 0;
    float pjx = 0.f, pjy = 0.f, pjz = 0.f;
    if (lane < KNN) {
        pjx = coord[3 * jv + 0];
        pjy = coord[3 * jv + 1];
        pjz = coord[3 * jv + 2];
    }

    float run_m = -INFINITY, run_l = 0.f;
    f4    accv = {0.f, 0.f, 0.f, 0.f};
    float acct = 0.f;
    float ax = 0.f, ay = 0.f, az = 0.f;

#pragma unroll 2
    for (int k = 0; k < KNN; ++k) {
        int j = __shfl(jv, k);
        const short* hj = hb + (size_t)j * DHID;
        bf16x4 gb = *(const bf16x4*)(hj + 4 * lane);   // 8 B
        float  gt = bf2f(hj[256 + lane]);              // 2 B
        f4 gv = { bf2f(gb[0]), bf2f(gb[1]), bf2f(gb[2]), bf2f(gb[3]) };

        float dot = hv[0] * gv[0];
        dot = fmaf(hv[1], gv[1], dot);
        dot = fmaf(hv[2], gv[2], dot);
        dot = fmaf(hv[3], gv[3], dot);
        dot = fmaf(ht, gt, dot);
        // butterfly: all 64 lanes end with the full 320-dot
#pragma unroll
        for (int off = 32; off; off >>= 1) dot += __shfl_xor(dot, off);

        float dx = cx - __shfl(pjx, k);
        float dy = cy - __shfl(pjy, k);
        float dz = cz - __shfl(pjz, k);
        float radial = dx * dx + dy * dy + dz * dz;
        float s = dot + 1.0f / (radial + 1e-8f);   // DIST_W = 1.0, EPS = 1e-8

        float nm = fmaxf(run_m, s);
        float sc = __expf(run_m - nm);             // first iter: exp(-inf)=0
        float w  = __expf(s - nm);
        run_l = run_l * sc + w;
        accv  = accv * sc + w * gv;
        acct  = acct * sc + w * gt;
        ax = ax * sc + w * dx;
        ay = ay * sc + w * dy;
        az = az * sc + w * dz;
        run_m = nm;
    }

    float inv = 1.0f / run_l;
    short* ao = aggb + (size_t)wid * DHID;
    bf16x4 o;
#pragma unroll
    for (int i = 0; i < 4; ++i) o[i] = f2bf(accv[i] * inv);
    *(bf16x4*)(ao + 4 * lane) = o;                // 8B store
    ao[256 + lane] = f2bf(acct * inv);

    if (lane == 0) {
        float s = inv / (float)KNN;   // mean over K of softmax-weighted diffs
        coord_out[3 * wid + 0] = cx + ax * s;
        coord_out[3 * wid + 1] = cy + ay * s;
        coord_out[3 * wid + 2] = cz + az * s;
    }
}

// ---------------------------------------------------------------------------
// Fused MLP: hout = silu([h|agg]@W1+b1)@W2 + b2 + h
// 512 threads = 8 waves, 32 rows/block, grid N/32 = 256.
// Wave w: row-tile rt = w&1 (16 rows), col-set cs = w>>1 (5 col-tiles).
// h1 aliased into zs (dead after GEMM1 — residual re-reads fp32 h from
// global). LDS 60 -> 40 KiB, restoring 4 blocks/CU while keeping the
// 32-row B-amortization. Barriers: stage | GEMM1 | bar | h1-write | bar | GEMM2.
// ---------------------------------------------------------------------------
__global__ __launch_bounds__(512)
void mlp_fused_kernel(const float* __restrict__ h,
                      const short* __restrict__ hb,
                      const short* __restrict__ aggb,
                      const short* __restrict__ Wt1,
                      const short* __restrict__ Wt2,
                      const float* __restrict__ b1,
                      const float* __restrict__ b2,
                      float*       __restrict__ hout)
{
    __shared__ short zs[32 * 640];      // 40 KiB: z-tile, then h1 alias

    const int tid  = threadIdx.x;
    const int lane = tid & 63;
    const int wv   = tid >> 6;          // 0..7
    const int rt   = wv & 1;            // row-tile 0/1
    const int cs   = wv >> 1;           // col-set 0..3
    const int lrow = lane & 15;
    const int kg   = lane >> 4;
    const int r0   = blockIdx.x * 32;

    // stage z = [hb | aggb]: 32 rows x 80 chunks of 8 shorts = 2560 chunks
    for (int c = tid; c < 2560; c += 512) {
        int row = c / 80;
        int zc  = (c - row * 80) * 8;   // 0..632
        int sw  = (row & 7) << 4;
        bf16x8 v;
        if (zc < DHID) {
            v = *(const bf16x8*)(hb + (size_t)(r0 + row) * DHID + zc);
        } else {
            v = *(const bf16x8*)(aggb + (size_t)(r0 + row) * DHID + (zc - DHID));
        }
        *(bf16x8*)((char*)zs + ((row * 1280 + zc * 2) ^ sw)) = v;
    }
    __syncthreads();

    const int   sw    = (lrow & 7) << 4;
    const char* abase = (const char*)zs + (rt * 16 + lrow) * 1280;

    // ---- GEMM1: [32 x 640] @ W1, 5 col-tiles/wave, 20 K-steps ----
    f32x4 acc[5] = {};
    {
        const short* B = Wt1 + (size_t)(cs * 5) * (20 * 512) + kg * 128 + lrow * 8;
        for (int t = 0; t < 20; ++t) {
            bf16x8 a = *(const bf16x8*)(abase + ((t * 64 + kg * 16) ^ sw));
#pragma unroll
            for (int i = 0; i < 5; ++i) {
                bf16x8 b = *(const bf16x8*)(B + (size_t)i * (20 * 512) + t * 512);
                acc[i] = __builtin_amdgcn_mfma_f32_16x16x32_bf16(a, b, acc[i], 0, 0, 0);
            }
        }
    }

    __syncthreads();   // all waves done READING zs before h1 overwrites it

    // epilogue 1: bias + SiLU -> h1 (aliased into zs, swizzled [32][320])
#pragma unroll
    for (int i = 0; i < 5; ++i) {
        int colc = (cs * 5 + i) * 16 + lrow;
        float bb = b1[colc];
#pragma unroll
        for (int r = 0; r < 4; ++r) {
            int row = rt * 16 + kg * 4 + r;
            float x = acc[i][r] + bb;
            x = x / (1.f + __expf(-x));
            *(short*)((char*)zs + ((row * 640 + colc * 2) ^ ((row & 7) << 4))) = f2bf(x);
        }
    }
    __syncthreads();

    // ---- GEMM2: [32 x 320] @ W2, 5 col-tiles/wave, 10 K-steps ----
    f32x4 acc2[5] = {};
    {
        const short* B = Wt2 + (size_t)(cs * 5) * (10 * 512) + kg * 128 + lrow * 8;
        const char* a2base = (const char*)zs + (rt * 16 + lrow) * 640;
        for (int t = 0; t < 10; ++t) {
            bf16x8 a = *(const bf16x8*)(a2base + ((t * 64 + kg * 16) ^ sw));
#pragma unroll
            for (int i = 0; i < 5; ++i) {
                bf16x8 b = *(const bf16x8*)(B + (size_t)i * (10 * 512) + t * 512);
                acc2[i] = __builtin_amdgcn_mfma_f32_16x16x32_bf16(a, b, acc2[i], 0, 0, 0);
            }
        }
    }

    // epilogue 2: bias + residual (fp32 h re-read) -> hout
#pragma unroll
    for (int i = 0; i < 5; ++i) {
        int colc = (cs * 5 + i) * 16 + lrow;
        float bb = b2[colc];
#pragma unroll
        for (int r = 0; r < 4; ++r) {
            int grow = r0 + rt * 16 + kg * 4 + r;
            hout[(size_t)grow * DHID + colc] =
                acc2[i][r] + bb + h[(size_t)grow * DHID + colc];
        }
    }
}

// ---------------------------------------------------------------------------
extern "C" void kernel_launch(void* const* d_in, const int* in_sizes, int n_in,
                              void* d_out, int out_size, void* d_ws, size_t ws_size,
                              hipStream_t stream)
{
    const float* h     = (const float*)d_in[0];
    const float* coord = (const float*)d_in[1];
    const float* W1    = (const float*)d_in[2];
    const float* b1    = (const float*)d_in[3];
    const float* W2    = (const float*)d_in[4];
    const float* b2    = (const float*)d_in[5];
    const int*   ei    = (const int*)d_in[6];   // [2, N*K] int32

    const int N  = in_sizes[0] / DHID;          // 8192
    const int NK = N * KNN;

    float* out       = (float*)d_out;
    float* hout      = out;                     // [N, 320]
    float* coord_out = out + (size_t)N * DHID;  // [N, 3]

    // ws layout (shorts): aggb[N*320] | Wt1[204800] | Wt2[102400] | hb[N*320]
    short* aggb = (short*)d_ws;
    short* Wt1  = aggb + (size_t)N * DHID;
    short* Wt2  = Wt1 + 20 * 20 * 512;
    short* hb   = Wt2 + 20 * 10 * 512;

    const int* col = ei + NK;                   // second row of edge_index

    const int conv_elems = 640 * 320 + 320 * 320 + N * DHID;
    conv_kernel<<<(conv_elems + 255) / 256, 256, 0, stream>>>(W1, W2, h, Wt1, Wt2, hb, N);
    edge_kernel<<<N / 4, 256, 0, stream>>>(h, hb, coord, col, aggb, coord_out, N);
    mlp_fused_kernel<<<N / 32, 512, 0, stream>>>(h, hb, aggb, Wt1, Wt2, b1, b2, hout);
}